// Round 1
// baseline (2541.374 us; speedup 1.0000x reference)
//
#include <hip/hip_runtime.h>
#include <hip/hip_bf16.h>

// Transformer block: embed+LN -> QKV -> causal flash attention -> proj+residual -> logits
// B=4 T=2048 D=1024 H=16 HD=64 V=32000, M = B*T = 8192.
// Strategy: bf16 MFMA (16x16x32) for all GEMMs; weights repacked per-call to B^T bf16.

typedef short short8 __attribute__((ext_vector_type(8)));   // 8 bf16 = 4 VGPRs (MFMA A/B frag)
typedef short short4v __attribute__((ext_vector_type(4)));
typedef float f32x4 __attribute__((ext_vector_type(4)));    // MFMA C/D frag

#define MFMA16(a, b, c) __builtin_amdgcn_mfma_f32_16x16x32_bf16(a, b, c, 0, 0, 0)

__device__ __forceinline__ short f2b(float f) {
    // round-to-nearest-even fp32 -> bf16
    unsigned u = __builtin_bit_cast(unsigned, f);
    u += 0x7fffu + ((u >> 16) & 1u);
    return (short)(u >> 16);
}

// ---------------------------------------------------------------------------
// Embedding + LayerNorm. One block per token row. x (fp32) kept for residual,
// h (bf16) feeds the QKV GEMM.
// ---------------------------------------------------------------------------
__global__ __launch_bounds__(256)
void embed_ln(const int* __restrict__ tokens, const float* __restrict__ tokE,
              const float* __restrict__ posE, const float* __restrict__ g,
              const float* __restrict__ bb, float* __restrict__ X,
              short* __restrict__ Hb) {
    __shared__ float red[8];
    const int row = blockIdx.x;          // b*T + t
    const int t = row & 2047;
    const int tok = tokens[row];
    const int i4 = threadIdx.x * 4;

    float4 v = *(const float4*)(tokE + (size_t)tok * 1024 + i4);
    float4 p = *(const float4*)(posE + (size_t)t * 1024 + i4);
    v.x += p.x; v.y += p.y; v.z += p.z; v.w += p.w;
    *(float4*)(X + (size_t)row * 1024 + i4) = v;

    float s = v.x + v.y + v.z + v.w;
    float sq = v.x * v.x + v.y * v.y + v.z * v.z + v.w * v.w;
    #pragma unroll
    for (int off = 1; off < 64; off <<= 1) {
        s += __shfl_xor(s, off, 64);
        sq += __shfl_xor(sq, off, 64);
    }
    const int wave = threadIdx.x >> 6, lane = threadIdx.x & 63;
    if (lane == 0) { red[wave] = s; red[4 + wave] = sq; }
    __syncthreads();
    s = red[0] + red[1] + red[2] + red[3];
    sq = red[4] + red[5] + red[6] + red[7];
    const float mu = s * (1.0f / 1024.0f);
    const float var = sq * (1.0f / 1024.0f) - mu * mu;
    const float rs = rsqrtf(var + 1e-5f);

    float4 gg = *(const float4*)(g + i4);
    float4 bv = *(const float4*)(bb + i4);
    short4v hv;
    hv[0] = f2b((v.x - mu) * rs * gg.x + bv.x);
    hv[1] = f2b((v.y - mu) * rs * gg.y + bv.y);
    hv[2] = f2b((v.z - mu) * rs * gg.z + bv.z);
    hv[3] = f2b((v.w - mu) * rs * gg.w + bv.w);
    *(short4v*)(Hb + (size_t)row * 1024 + i4) = hv;
}

// ---------------------------------------------------------------------------
// Weight repacks: fp32 [K][N]-ish -> bf16 B^T [N][K=1024] (contiguous K for
// the MFMA B-fragment). Coalesced writes; strided reads ride L2/L3.
// ---------------------------------------------------------------------------
__global__ __launch_bounds__(256)
void repack_qkv(const float* __restrict__ Wq, const float* __restrict__ Wk,
                const float* __restrict__ Wv, short* __restrict__ Bt) {
    const int o = blockIdx.x * 256 + threadIdx.x;     // n*1024 + k, n in [0,3072)
    const int n = o >> 10, k = o & 1023;
    const int mat = n >> 10, r = n & 1023;
    const int h = r >> 6, hd = r & 63;
    const float* W = (mat == 0) ? Wq : (mat == 1) ? Wk : Wv;
    Bt[o] = f2b(W[(h << 16) + (k << 6) + hd]);        // Wx[h][k][hd]
}

__global__ __launch_bounds__(256)
void repack_mat(const float* __restrict__ W, short* __restrict__ Bt, int N) {
    const int o = blockIdx.x * 256 + threadIdx.x;     // n*1024 + k
    const int n = o >> 10, k = o & 1023;
    Bt[o] = f2b(W[(size_t)k * N + n]);
}

// ---------------------------------------------------------------------------
// 128x128-tile bf16 MFMA GEMM, C = A[M,K] * Bt[N,K]^T. 4 waves, each 64x64
// (4x4 frags of 16x16x32). BK=32. EPI: 0 = bf16 C store (ld=N),
// 1 = +fp32 residual -> bf16, 2 = +bias -> fp32 out.
// ---------------------------------------------------------------------------
template <int EPI>
__global__ __launch_bounds__(256)
void gemm128(const short* __restrict__ A, const short* __restrict__ Bt,
             const int K, const int N,
             short* __restrict__ Cb,
             const float* __restrict__ Xres, short* __restrict__ Xb,
             float* __restrict__ Of, const float* __restrict__ bias) {
    __shared__ short As[128 * 32];
    __shared__ short Bs[128 * 32];
    const int tid = threadIdx.x, wave = tid >> 6, lane = tid & 63;
    const int quad = lane >> 4, l16 = lane & 15;
    const int wm = wave >> 1, wn = wave & 1;
    const int m0 = blockIdx.y * 128, n0 = blockIdx.x * 128;

    f32x4 acc[4][4];
    #pragma unroll
    for (int i = 0; i < 4; i++)
        #pragma unroll
        for (int j = 0; j < 4; j++) acc[i][j] = f32x4{0.f, 0.f, 0.f, 0.f};

    const int c0 = tid, c1 = tid + 256;               // 512 chunks of 8 bf16 per tile
    const int ra0 = c0 >> 2, ka0 = (c0 & 3) * 8;
    const int ra1 = c1 >> 2, ka1 = (c1 & 3) * 8;

    for (int kk = 0; kk < K; kk += 32) {
        __syncthreads();
        *(short8*)&As[ra0 * 32 + ka0] = *(const short8*)&A[(size_t)(m0 + ra0) * K + kk + ka0];
        *(short8*)&As[ra1 * 32 + ka1] = *(const short8*)&A[(size_t)(m0 + ra1) * K + kk + ka1];
        *(short8*)&Bs[ra0 * 32 + ka0] = *(const short8*)&Bt[(size_t)(n0 + ra0) * K + kk + ka0];
        *(short8*)&Bs[ra1 * 32 + ka1] = *(const short8*)&Bt[(size_t)(n0 + ra1) * K + kk + ka1];
        __syncthreads();

        short8 af[4], bf[4];
        #pragma unroll
        for (int mb = 0; mb < 4; mb++)
            af[mb] = *(const short8*)&As[(wm * 64 + mb * 16 + l16) * 32 + quad * 8];
        #pragma unroll
        for (int nb = 0; nb < 4; nb++)
            bf[nb] = *(const short8*)&Bs[(wn * 64 + nb * 16 + l16) * 32 + quad * 8];
        #pragma unroll
        for (int mb = 0; mb < 4; mb++)
            #pragma unroll
            for (int nb = 0; nb < 4; nb++)
                acc[mb][nb] = MFMA16(af[mb], bf[nb], acc[mb][nb]);
    }

    // C layout: col = lane&15, row = quad*4 + r (m89/m91-verified)
    #pragma unroll
    for (int mb = 0; mb < 4; mb++) {
        #pragma unroll
        for (int r = 0; r < 4; r++) {
            const int row = m0 + wm * 64 + mb * 16 + quad * 4 + r;
            #pragma unroll
            for (int nb = 0; nb < 4; nb++) {
                const int col = n0 + wn * 64 + nb * 16 + l16;
                const float v = acc[mb][nb][r];
                if constexpr (EPI == 0) {
                    Cb[(size_t)row * N + col] = f2b(v);
                } else if constexpr (EPI == 1) {
                    const float xv = Xres[(size_t)row * N + col] + v;
                    Xb[(size_t)row * N + col] = f2b(xv);
                } else {
                    Of[(size_t)row * N + col] = v + bias[col];
                }
            }
        }
    }
}

// ---------------------------------------------------------------------------
// Flash attention, causal, HD=64. Block = (qt, h, b): 64 q-rows, 4 waves of 16
// rows each. QK^T and PV via MFMA; online softmax with 16-lane shuffle
// reductions; P round-trips through LDS (C-layout -> A-layout).
// ---------------------------------------------------------------------------
__global__ __launch_bounds__(256)
void attn_flash(const short* __restrict__ qkv, short* __restrict__ attn_out) {
    __shared__ short Kt[64 * 64];        // [s][d]
    __shared__ short Vt[64 * 64];        // [d][s]  (transposed for B-frag)
    __shared__ short Pl[4][16 * 64];     // per-wave P [t][s]
    const int qt = blockIdx.x, h = blockIdx.y, b = blockIdx.z;
    const int tid = threadIdx.x, wave = tid >> 6, lane = tid & 63;
    const int quad = lane >> 4, l16 = lane & 15;

    // Q A-fragments, kept in registers for the whole kernel
    const int t_frag = qt * 64 + wave * 16 + l16;
    const size_t qbase = (size_t)(b * 2048 + t_frag) * 3072 + h * 64;
    const short8 aq0 = *(const short8*)(qkv + qbase + quad * 8);
    const short8 aq1 = *(const short8*)(qkv + qbase + 32 + quad * 8);

    f32x4 oacc[4];
    float m_run[4], l_run[4];
    #pragma unroll
    for (int i = 0; i < 4; i++) {
        oacc[i] = f32x4{0.f, 0.f, 0.f, 0.f};
        m_run[i] = -3.0e38f;
        l_run[i] = 0.f;
    }
    const int t_out = qt * 64 + wave * 16 + quad * 4;   // + r

    for (int kt = 0; kt <= qt; kt++) {
        const int s0 = kt * 64;
        __syncthreads();   // protect Kt/Vt from overwrite while others compute
        // stage K tile (as-is) and V tile (transposed): 2 chunks of 8 per thread
        #pragma unroll
        for (int cc = 0; cc < 2; cc++) {
            const int c = tid + cc * 256;
            const int sl = c >> 3, dc = c & 7;
            const size_t rbase = (size_t)(b * 2048 + s0 + sl) * 3072 + h * 64 + dc * 8;
            *(short8*)&Kt[sl * 64 + dc * 8] = *(const short8*)(qkv + rbase + 1024);
            const short8 vv = *(const short8*)(qkv + rbase + 2048);
            #pragma unroll
            for (int j = 0; j < 8; j++) Vt[(dc * 8 + j) * 64 + sl] = vv[j];
        }
        __syncthreads();

        // S = Q K^T * scale  (16 t-rows x 64 keys per wave)
        float sv[4][4];
        #pragma unroll
        for (int nb = 0; nb < 4; nb++) {
            f32x4 sc = f32x4{0.f, 0.f, 0.f, 0.f};
            const short* kr = &Kt[(nb * 16 + l16) * 64 + quad * 8];
            sc = MFMA16(aq0, *(const short8*)kr, sc);
            sc = MFMA16(aq1, *(const short8*)(kr + 32), sc);
            #pragma unroll
            for (int r = 0; r < 4; r++) sv[nb][r] = sc[r] * 0.125f;
        }
        if (kt == qt) {   // diagonal tile: mask s > t
            #pragma unroll
            for (int nb = 0; nb < 4; nb++) {
                const int s_g = s0 + nb * 16 + l16;
                #pragma unroll
                for (int r = 0; r < 4; r++)
                    if (s_g > t_out + r) sv[nb][r] = -3.0e38f;
            }
        }
        // online softmax per t-row (row lives across 16 lanes of a quad-group)
        #pragma unroll
        for (int r = 0; r < 4; r++) {
            float vm = fmaxf(fmaxf(sv[0][r], sv[1][r]), fmaxf(sv[2][r], sv[3][r]));
            #pragma unroll
            for (int off = 1; off < 16; off <<= 1) vm = fmaxf(vm, __shfl_xor(vm, off, 16));
            const float mn = fmaxf(m_run[r], vm);
            const float alpha = __expf(m_run[r] - mn);
            m_run[r] = mn;
            float ps = 0.f;
            #pragma unroll
            for (int nb = 0; nb < 4; nb++) {
                const float p = __expf(sv[nb][r] - mn);
                sv[nb][r] = p;
                ps += p;
            }
            #pragma unroll
            for (int off = 1; off < 16; off <<= 1) ps += __shfl_xor(ps, off, 16);
            l_run[r] = l_run[r] * alpha + ps;
            #pragma unroll
            for (int nb = 0; nb < 4; nb++) {
                oacc[nb][r] *= alpha;
                Pl[wave][(quad * 4 + r) * 64 + nb * 16 + l16] = f2b(sv[nb][r]);
            }
        }
        // O += P V   (P re-read in A-layout; per-wave LDS region, no barrier)
        #pragma unroll
        for (int ks = 0; ks < 2; ks++) {
            const short8 ap = *(const short8*)&Pl[wave][l16 * 64 + ks * 32 + quad * 8];
            #pragma unroll
            for (int nb = 0; nb < 4; nb++) {
                const short8 bv = *(const short8*)&Vt[(nb * 16 + l16) * 64 + ks * 32 + quad * 8];
                oacc[nb] = MFMA16(ap, bv, oacc[nb]);
            }
        }
    }

    #pragma unroll
    for (int r = 0; r < 4; r++) {
        const float inv = 1.0f / l_run[r];
        const size_t obase = (size_t)(b * 2048 + t_out + r) * 1024 + h * 64 + l16;
        #pragma unroll
        for (int nb = 0; nb < 4; nb++)
            attn_out[obase + nb * 16] = f2b(oacc[nb][r] * inv);
    }
}

// ---------------------------------------------------------------------------
// Workspace layout (bytes). Total = 208,142,336 (~199 MB).
// ---------------------------------------------------------------------------
static constexpr size_t OFF_X    = 0;                         // 8192*1024 fp32  (32 MB)
static constexpr size_t OFF_H    = OFF_X + 33554432;          // 8192*1024 bf16  (16 MB)
static constexpr size_t OFF_QKV  = OFF_H + 16777216;          // 8192*3072 bf16  (48 MB)
static constexpr size_t OFF_ATT  = OFF_QKV + 50331648;        // 8192*1024 bf16  (16 MB)
static constexpr size_t OFF_XB   = OFF_ATT + 16777216;        // 8192*1024 bf16  (16 MB)
static constexpr size_t OFF_WQKV = OFF_XB + 16777216;         // 3072*1024 bf16  (6 MB)
static constexpr size_t OFF_WPRJ = OFF_WQKV + 6291456;        // 1024*1024 bf16  (2 MB)
static constexpr size_t OFF_FCW  = OFF_WPRJ + 2097152;        // 32000*1024 bf16 (64 MB)

extern "C" void kernel_launch(void* const* d_in, const int* in_sizes, int n_in,
                              void* d_out, int out_size, void* d_ws, size_t ws_size,
                              hipStream_t stream) {
    const int*   tokens = (const int*)d_in[0];
    const float* tokE   = (const float*)d_in[1];
    const float* posE   = (const float*)d_in[2];
    const float* ln_g   = (const float*)d_in[3];
    const float* ln_b   = (const float*)d_in[4];
    const float* Wq     = (const float*)d_in[5];
    const float* Wk     = (const float*)d_in[6];
    const float* Wv     = (const float*)d_in[7];
    const float* Wproj  = (const float*)d_in[8];
    const float* fcw    = (const float*)d_in[9];
    const float* fcb    = (const float*)d_in[10];
    float* out = (float*)d_out;

    char* ws = (char*)d_ws;
    float* x_f32  = (float*)(ws + OFF_X);
    short* h_bf   = (short*)(ws + OFF_H);
    short* qkv    = (short*)(ws + OFF_QKV);
    short* attnb  = (short*)(ws + OFF_ATT);
    short* x_bf   = (short*)(ws + OFF_XB);
    short* wqkvT  = (short*)(ws + OFF_WQKV);
    short* wprjT  = (short*)(ws + OFF_WPRJ);
    short* fcwT   = (short*)(ws + OFF_FCW);

    // independent prep
    embed_ln<<<8192, 256, 0, stream>>>(tokens, tokE, posE, ln_g, ln_b, x_f32, h_bf);
    repack_qkv<<<12288, 256, 0, stream>>>(Wq, Wk, Wv, wqkvT);
    repack_mat<<<4096, 256, 0, stream>>>(Wproj, wprjT, 1024);
    repack_mat<<<128000, 256, 0, stream>>>(fcw, fcwT, 32000);

    // QKV: [8192,1024] x [1024,3072] -> qkv bf16 [8192][3072]
    gemm128<0><<<dim3(24, 64), 256, 0, stream>>>(h_bf, wqkvT, 1024, 3072,
                                                 qkv, nullptr, nullptr, nullptr, nullptr);
    // causal flash attention -> attnb bf16 [8192][1024] (head-concat layout)
    attn_flash<<<dim3(32, 16, 4), 256, 0, stream>>>(qkv, attnb);
    // proj + residual: x = x_embed + attn @ Wproj -> x_bf
    gemm128<1><<<dim3(8, 64), 256, 0, stream>>>(attnb, wprjT, 1024, 1024,
                                                nullptr, x_f32, x_bf, nullptr, nullptr);
    // logits: x @ fc_w + fc_b -> fp32 out [8192][32000]
    gemm128<2><<<dim3(250, 64), 256, 0, stream>>>(x_bf, fcwT, 1024, 32000,
                                                  nullptr, nullptr, nullptr, out, fcb);
}